// Round 3
// baseline (71.972 us; speedup 1.0000x reference)
//
#include <hip/hip_runtime.h>
#include <hip/hip_bf16.h>

#define B_DIM 32
#define T_DIM 2048
#define D_DIM 1024
#define S_MAXK 32

// ws layout (bytes):
//   hp     float[2][B][32][D] @ 0        : 8,388,608  (raw partial sums, per t-half)
//   counts uint [2][B][32]    @ 8388608  : 8,192
//   pos    uint [2][B][32]    @ 8396800  : 8,192
//   ctrl   {float tot, float num, uint done} @ 8404992
#define HP_OFF     0
#define COUNTS_OFF 8388608
#define POS_OFF    8396800
#define CTRL_OFF   8404992
#define HALF_STRIDE (B_DIM * S_MAXK * D_DIM)   // floats between half-buffers

// One block per (b, step, t-half). Scan sid half-row -> match list in LDS,
// then register-accumulate |x| over matching rows with 4-deep batched loads.
// grid = 2048 -> 8 blocks/CU -> full wave occupancy.
__global__ __launch_bounds__(256) void k_gather(const float* __restrict__ x,
                                                const int* __restrict__ sid,
                                                float* __restrict__ hp,
                                                unsigned* __restrict__ counts,
                                                unsigned* __restrict__ pos,
                                                float* __restrict__ ctrl) {
    __shared__ int      list[T_DIM / 2];
    __shared__ int      cnt;
    __shared__ unsigned firstpos;

    const int b    = blockIdx.x >> 6;
    const int s    = (blockIdx.x >> 1) & 31;     // step value = s+1
    const int half = blockIdx.x & 1;
    const int tid  = threadIdx.x;

    if (blockIdx.x == 0 && tid == 0) {           // reset cross-call control block
        ctrl[0] = 0.0f; ctrl[1] = 0.0f; ((unsigned*)ctrl)[2] = 0u;
    }
    if (tid == 0) { cnt = 0; firstpos = 0xFFFFFFFFu; }
    __syncthreads();

    const int t0base = half * (T_DIM / 2);
    const int* srow = sid + b * T_DIM + t0base;
    unsigned myfirst = 0xFFFFFFFFu;
    for (int t = tid; t < T_DIM / 2; t += 256) {
        if (srow[t] == s + 1) {
            int idx = atomicAdd(&cnt, 1);        // LDS atomic
            list[idx] = t0base + t;
            if ((unsigned)(t0base + t) < myfirst) myfirst = (unsigned)(t0base + t);
        }
    }
    if (myfirst != 0xFFFFFFFFu) atomicMin(&firstpos, myfirst);
    __syncthreads();

    const int n = cnt;
    const float4* xb = (const float4*)(x + (size_t)b * T_DIM * D_DIM);
    const int dcol = tid;                        // float4 column: d = tid*4
    float4 acc = {0.f, 0.f, 0.f, 0.f};

    int i = 0;
    for (; i + 4 <= n; i += 4) {
        int i0 = list[i], i1 = list[i + 1], i2 = list[i + 2], i3 = list[i + 3];
        float4 v0 = xb[(size_t)i0 * (D_DIM / 4) + dcol];
        float4 v1 = xb[(size_t)i1 * (D_DIM / 4) + dcol];
        float4 v2 = xb[(size_t)i2 * (D_DIM / 4) + dcol];
        float4 v3 = xb[(size_t)i3 * (D_DIM / 4) + dcol];
        acc.x += fabsf(v0.x) + fabsf(v1.x) + fabsf(v2.x) + fabsf(v3.x);
        acc.y += fabsf(v0.y) + fabsf(v1.y) + fabsf(v2.y) + fabsf(v3.y);
        acc.z += fabsf(v0.z) + fabsf(v1.z) + fabsf(v2.z) + fabsf(v3.z);
        acc.w += fabsf(v0.w) + fabsf(v1.w) + fabsf(v2.w) + fabsf(v3.w);
    }
    for (; i < n; ++i) {
        float4 v = xb[(size_t)list[i] * (D_DIM / 4) + dcol];
        acc.x += fabsf(v.x); acc.y += fabsf(v.y);
        acc.z += fabsf(v.z); acc.w += fabsf(v.w);
    }

    ((float4*)(hp + ((size_t)(half * B_DIM * S_MAXK) + b * 32 + s) * D_DIM))[dcol] =
        make_float4(acc.x, acc.y, acc.z, acc.w);

    if (tid == 0) {
        counts[half * 1024 + b * 32 + s] = (unsigned)n;
        pos[half * 1024 + b * 32 + s] = (n > 0) ? firstpos : (unsigned)T_DIM;
    }
}

// One block per b: merge halves, argsort pos, pairwise E, per-b loss, then
// atomic accumulate into ctrl; last block writes out = tot/(num+1e-9).
__global__ __launch_bounds__(256) void k_pairs(const float* __restrict__ hp,
                                               const unsigned* __restrict__ counts,
                                               const unsigned* __restrict__ pos,
                                               const int* __restrict__ labels,
                                               float* __restrict__ ctrl,
                                               float* __restrict__ out) {
    const int b = blockIdx.x;
    const int tid = threadIdx.x;
    __shared__ unsigned posl[32];
    __shared__ float    rcp[32];
    __shared__ int      ordl[32];
    __shared__ float    El[31];

    if (tid < 32) {
        unsigned c = counts[b * 32 + tid] + counts[1024 + b * 32 + tid];
        rcp[tid] = 1.0f / (float)(c > 1u ? c : 1u);
        unsigned p0 = pos[b * 32 + tid], p1 = pos[1024 + b * 32 + tid];
        posl[tid] = p0 < p1 ? p0 : p1;
    }
    __syncthreads();
    if (tid < 32) {
        unsigned ps = posl[tid];
        int r = 0;
        for (int j = 0; j < 32; ++j) {
            unsigned pj = posl[j];
            if (pj < ps || (pj == ps && j < tid)) r++;
        }
        ordl[r] = tid;   // stable argsort of pos
    }
    __syncthreads();

    const int wave = tid >> 6;
    const int lane = tid & 63;
    for (int i = wave; i < 31; i += 4) {
        int A  = ordl[i];
        int B2 = ordl[i + 1];
        const float* a0 = &hp[((size_t)b * 32 + A)  * D_DIM];
        const float* a1 = a0 + HALF_STRIDE;
        const float* b0 = &hp[((size_t)b * 32 + B2) * D_DIM];
        const float* b1 = b0 + HALF_STRIDE;
        float ra = rcp[A], rb = rcp[B2];
        float ssum = 0.0f;
        for (int d = lane * 4; d < D_DIM; d += 256) {
            float4 x0 = *(const float4*)(a0 + d);
            float4 x1 = *(const float4*)(a1 + d);
            float4 y0 = *(const float4*)(b0 + d);
            float4 y1 = *(const float4*)(b1 + d);
            float d0 = fmaxf((x0.x + x1.x) * ra - (y0.x + y1.x) * rb, 0.0f);
            float d1 = fmaxf((x0.y + x1.y) * ra - (y0.y + y1.y) * rb, 0.0f);
            float d2 = fmaxf((x0.z + x1.z) * ra - (y0.z + y1.z) * rb, 0.0f);
            float d3 = fmaxf((x0.w + x1.w) * ra - (y0.w + y1.w) * rb, 0.0f);
            ssum += d0 * d0 + d1 * d1 + d2 * d2 + d3 * d3;
        }
        #pragma unroll
        for (int off = 32; off; off >>= 1) ssum += __shfl_down(ssum, off);
        if (lane == 0) El[i] = ssum * (1.0f / D_DIM);
    }
    __syncthreads();

    if (tid == 0) {
        float lpos = 0.0f, lneg = 0.0f;
        int np = 0, ni = 0, n = 0;
        for (int s2 = 0; s2 < 32; ++s2) n += (posl[s2] < T_DIM) ? 1 : 0;
        for (int i = 0; i < 31; ++i) {
            int A  = ordl[i];
            int B2 = ordl[i + 1];
            if (posl[B2] < T_DIM) {         // pair_valid
                float E = El[i];
                np++; lpos += E;
                if (A > B2) {               // inversion in step order
                    ni++; lneg += fmaxf(1.0f - E, 0.0f);   // ALPHA = 1
                }
            }
        }
        float loss_pos = lpos / (float)(np > 1 ? np : 1);
        float loss_neg = lneg / (float)(ni > 1 ? ni : 1);
        int lab = labels[b];
        bool pc = (lab == 1) && (n >= 2);
        bool nc = (lab == 0) && (ni > 0);
        float contrib = (pc ? loss_pos : 0.0f) + (nc ? loss_neg : 0.0f);
        float cntf = (float)((pc ? 1 : 0) + (nc ? 1 : 0));

        atomicAdd(&ctrl[0], contrib);
        atomicAdd(&ctrl[1], cntf);
        __threadfence();
        unsigned old = atomicAdd(&((unsigned*)ctrl)[2], 1u);
        if (old == (unsigned)(B_DIM - 1)) {      // true last block (ctrl[2] reset each call)
            float tot = atomicAdd(&ctrl[0], 0.0f);   // coherent read
            float num = atomicAdd(&ctrl[1], 0.0f);
            out[0] = tot / (num + 1e-9f);
        }
    }
}

extern "C" void kernel_launch(void* const* d_in, const int* in_sizes, int n_in,
                              void* d_out, int out_size, void* d_ws, size_t ws_size,
                              hipStream_t stream) {
    const float* x      = (const float*)d_in[0];
    const int*   sid    = (const int*)d_in[1];
    const int*   labels = (const int*)d_in[2];
    float* out = (float*)d_out;
    char*  ws  = (char*)d_ws;

    float*    hp     = (float*)(ws + HP_OFF);
    unsigned* counts = (unsigned*)(ws + COUNTS_OFF);
    unsigned* pos    = (unsigned*)(ws + POS_OFF);
    float*    ctrl   = (float*)(ws + CTRL_OFF);

    k_gather<<<B_DIM * S_MAXK * 2, 256, 0, stream>>>(x, sid, hp, counts, pos, ctrl);
    k_pairs<<<B_DIM, 256, 0, stream>>>(hp, counts, pos, labels, ctrl, out);
}